// Round 3
// baseline (3668.790 us; speedup 1.0000x reference)
//
#include <hip/hip_runtime.h>
#include <hip/hip_bf16.h>
#include <math.h>

#define EPS 1e-5f

typedef __hip_bfloat16 bf16;

__device__ __forceinline__ float toF(float v) { return v; }
__device__ __forceinline__ float toF(bf16 v) { return __bfloat162float(v); }
__device__ __forceinline__ void stF(float* p, float v) { *p = v; }
__device__ __forceinline__ void stF(bf16* p, float v) { *p = __float2bfloat16(v); }

// ---------------- block reduction (blockDim.x == 256 required) ----------------
__device__ __forceinline__ float block_reduce_sum(float v) {
    __shared__ float s[256];
    int t = threadIdx.x;
    s[t] = v;
    __syncthreads();
    #pragma unroll
    for (int st = 128; st > 0; st >>= 1) {
        if (t < st) s[t] += s[t + st];
        __syncthreads();
    }
    float r = s[0];
    __syncthreads();
    return r;
}

// ---------------- ternarize: one block per output filter ----------------
__global__ void ternarize_kernel(const float* __restrict__ w, float* __restrict__ wt, int K) {
    int f = blockIdx.x;
    const float* wf = w + (size_t)f * K;
    float* wtf = wt + (size_t)f * K;

    float s = 0.f;
    for (int i = threadIdx.x; i < K; i += blockDim.x) s += fabsf(wf[i]);
    float total = block_reduce_sum(s);
    float delta = 0.7f * total / (float)K;

    float sm = 0.f, cm = 0.f;
    for (int i = threadIdx.x; i < K; i += blockDim.x) {
        float a = fabsf(wf[i]);
        if (a > delta) { sm += a; cm += 1.f; }
    }
    sm = block_reduce_sum(sm);
    cm = block_reduce_sum(cm);
    float alpha = sm / (cm + 1e-8f);

    for (int i = threadIdx.x; i < K; i += blockDim.x) {
        float v = wf[i];
        float a = fabsf(v);
        wtf[i] = (a > delta) ? ((v > 0.f) ? alpha : -alpha) : 0.f;
    }
}

// ---------------- BN stats -> per-channel scale/shift ----------------
// scale[c] = g[c]*rsqrt(var+eps); shift[c] = b[c] - mean[c]*scale[c]
template <typename T>
__global__ void bn_stats_kernel(const T* __restrict__ src,
                                const float* __restrict__ g, const float* __restrict__ b,
                                float* __restrict__ scale, float* __restrict__ shift,
                                int C, int spatial, int N) {
    int c = blockIdx.x;
    float s = 0.f, s2 = 0.f;
    for (int n = 0; n < N; n++) {
        const T* p = src + ((size_t)n * C + c) * spatial;
        for (int i = threadIdx.x; i < spatial; i += blockDim.x) {
            float v = toF(p[i]);
            s += v;
            s2 += v * v;
        }
    }
    s = block_reduce_sum(s);
    s2 = block_reduce_sum(s2);
    if (threadIdx.x == 0) {
        float cnt = (float)N * (float)spatial;
        float mean = s / cnt;
        float var = fmaxf(s2 / cnt - mean * mean, 0.f);
        float r = rsqrtf(var + EPS);
        float sc = g[c] * r;
        scale[c] = sc;
        shift[c] = b[c] - mean * sc;
    }
}

// ---------------- 1x1 conv (optionally strided, optional input affine) ----------------
template <int COPT, bool AFFINE, typename TIn, typename TOut>
__global__ void conv1x1_kernel(const TIn* __restrict__ in, const float* __restrict__ wt,
                               const float* __restrict__ scale, const float* __restrict__ shift,
                               TOut* __restrict__ out,
                               int Cin, int Cout, int Hin, int Win, int Hout, int Wout, int stride) {
    int n = blockIdx.z;
    int co0 = blockIdx.y * COPT;
    int p = blockIdx.x * blockDim.x + threadIdx.x;
    int spatial_out = Hout * Wout;
    if (p >= spatial_out) return;
    int oh = p / Wout;
    int ow = p - oh * Wout;
    int in_off = (oh * stride) * Win + (ow * stride);
    int spatial_in = Hin * Win;
    const TIn* inp = in + (size_t)n * Cin * spatial_in + in_off;

    float acc[COPT];
    #pragma unroll
    for (int j = 0; j < COPT; j++) acc[j] = 0.f;

    for (int ci = 0; ci < Cin; ci++) {
        float v = toF(inp[(size_t)ci * spatial_in]);
        if (AFFINE) v = v * scale[ci] + shift[ci];
        #pragma unroll
        for (int j = 0; j < COPT; j++)
            acc[j] = fmaf(wt[(size_t)(co0 + j) * Cin + ci], v, acc[j]);
    }
    TOut* op = out + ((size_t)n * Cout + co0) * spatial_out + p;
    #pragma unroll
    for (int j = 0; j < COPT; j++) stF(&op[(size_t)j * spatial_out], acc[j]);
}

// ---------------- 3x3 conv, stride 2, pad 1, input affine (bf16 in/out) ----------------
template <int COPT>
__global__ void conv3x3_kernel(const bf16* __restrict__ in, const float* __restrict__ wt,
                               const float* __restrict__ scale, const float* __restrict__ shift,
                               bf16* __restrict__ out,
                               int Cin, int Cout, int Hin, int Win, int Hout, int Wout) {
    int n = blockIdx.y;
    int co0 = blockIdx.x * COPT;
    int p = threadIdx.x;
    int spatial_out = Hout * Wout;
    if (p >= spatial_out) return;
    int oh = p / Wout;
    int ow = p - oh * Wout;
    int spatial_in = Hin * Win;
    const bf16* inb = in + (size_t)n * Cin * spatial_in;

    float acc[COPT];
    #pragma unroll
    for (int j = 0; j < COPT; j++) acc[j] = 0.f;

    for (int ci = 0; ci < Cin; ci++) {
        const bf16* inc = inb + (size_t)ci * spatial_in;
        float sc = scale[ci], sh = shift[ci];
        const float* wq = wt + ((size_t)co0 * Cin + ci) * 9;
        #pragma unroll
        for (int kh = 0; kh < 3; kh++) {
            int ih = oh * 2 - 1 + kh;
            if (ih < 0 || ih >= Hin) continue;
            #pragma unroll
            for (int kw = 0; kw < 3; kw++) {
                int iw = ow * 2 - 1 + kw;
                if (iw < 0 || iw >= Win) continue;
                float v = toF(inc[ih * Win + iw]) * sc + sh;
                int k = kh * 3 + kw;
                #pragma unroll
                for (int j = 0; j < COPT; j++)
                    acc[j] = fmaf(wq[(size_t)j * Cin * 9 + k], v, acc[j]);
            }
        }
    }
    bf16* op = out + ((size_t)n * Cout + co0) * spatial_out + p;
    #pragma unroll
    for (int j = 0; j < COPT; j++) stF(&op[(size_t)j * spatial_out], acc[j]);
}

// ---------------- final: out += sc_conv*scale + shift ----------------
__global__ void bn_add_kernel(const bf16* __restrict__ scv,
                              const float* __restrict__ scale, const float* __restrict__ shift,
                              float* __restrict__ out, int C, int spatial, size_t total) {
    size_t i = (size_t)blockIdx.x * blockDim.x + threadIdx.x;
    if (i >= total) return;
    int c = (int)((i / (size_t)spatial) % (size_t)C);
    out[i] += toF(scv[i]) * scale[c] + shift[c];
}

extern "C" void kernel_launch(void* const* d_in, const int* in_sizes, int n_in,
                              void* d_out, int out_size, void* d_ws, size_t ws_size,
                              hipStream_t stream) {
    const float* x      = (const float*)d_in[0];   // (64,512,28,28)
    const float* bn1_g  = (const float*)d_in[1];
    const float* bn1_b  = (const float*)d_in[2];
    const float* w1     = (const float*)d_in[3];   // (256,512,1,1)
    const float* bn2_g  = (const float*)d_in[4];
    const float* bn2_b  = (const float*)d_in[5];
    const float* w2     = (const float*)d_in[6];   // (256,256,3,3)
    const float* bn3_g  = (const float*)d_in[7];
    const float* bn3_b  = (const float*)d_in[8];
    const float* w3     = (const float*)d_in[9];   // (1024,256,1,1)
    const float* ds_w   = (const float*)d_in[10];  // (1024,512,1,1) — NOT ternarized!
    const float* dbn_g  = (const float*)d_in[11];
    const float* dbn_b  = (const float*)d_in[12];
    float* out = (float*)d_out;

    const int N = 64, C1 = 512, C2 = 256, C3 = 1024;
    const int H = 28, W = 28, Ho = 14, Wo = 14;
    const int SP1 = H * W;      // 784
    const int SP2 = Ho * Wo;    // 196

    // workspace layout (bytes) — total ~34 MiB
    char* wsb = (char*)d_ws;
    size_t off = 0;
    bf16* h1 = (bf16*)(wsb + off); off += (size_t)N * C2 * SP1 * sizeof(bf16);  // 25.7 MB
    bf16* h2 = (bf16*)(wsb + off); off += (size_t)N * C2 * SP2 * sizeof(bf16);  // 6.4 MB
    // sc aliases h1's region: h1 (64*256*784 elems) == sc (64*1024*196 elems),
    // h1 is dead after conv2 and sc is written strictly later in stream order.
    bf16* sc = h1;
    float* w1t  = (float*)(wsb + off); off += (size_t)C2 * C1 * sizeof(float);
    float* w2t  = (float*)(wsb + off); off += (size_t)C2 * C2 * 9 * sizeof(float);
    float* w3t  = (float*)(wsb + off); off += (size_t)C3 * C2 * sizeof(float);
    float* scale1 = (float*)(wsb + off); off += C1 * sizeof(float);
    float* shift1 = (float*)(wsb + off); off += C1 * sizeof(float);
    float* scale2 = (float*)(wsb + off); off += C2 * sizeof(float);
    float* shift2 = (float*)(wsb + off); off += C2 * sizeof(float);
    float* scale3 = (float*)(wsb + off); off += C2 * sizeof(float);
    float* shift3 = (float*)(wsb + off); off += C2 * sizeof(float);
    float* scaled = (float*)(wsb + off); off += C3 * sizeof(float);
    float* shiftd = (float*)(wsb + off); off += C3 * sizeof(float);
    (void)ws_size; (void)in_sizes; (void)n_in; (void)out_size;

    // 1) ternarize weights (w1, w2, w3 only — ds_w stays full-precision per reference)
    ternarize_kernel<<<C2, 256, 0, stream>>>(w1, w1t, C1);          // 256 filters, K=512
    ternarize_kernel<<<C2, 256, 0, stream>>>(w2, w2t, C2 * 9);      // 256 filters, K=2304
    ternarize_kernel<<<C3, 256, 0, stream>>>(w3, w3t, C2);          // 1024 filters, K=256

    // 2) bn1 stats on x (fp32 input)
    bn_stats_kernel<float><<<C1, 256, 0, stream>>>(x, bn1_g, bn1_b, scale1, shift1, C1, SP1, N);

    // 3) conv1: h1 = conv1x1(bn1(x), w1t)   [N,256,28,28] bf16
    {
        dim3 grid((SP1 + 255) / 256, C2 / 8, N);
        conv1x1_kernel<8, true, float, bf16><<<grid, 256, 0, stream>>>(
            x, w1t, scale1, shift1, h1, C1, C2, H, W, H, W, 1);
    }

    // 4) bn2 stats on h1 (bf16)
    bn_stats_kernel<bf16><<<C2, 256, 0, stream>>>(h1, bn2_g, bn2_b, scale2, shift2, C2, SP1, N);

    // 5) conv2: h2 = conv3x3(bn2(h1), w2t, stride2, pad1)  [N,256,14,14] bf16
    {
        dim3 grid(C2 / 8, N);
        conv3x3_kernel<8><<<grid, 256, 0, stream>>>(h1, w2t, scale2, shift2, h2,
                                                    C2, C2, H, W, Ho, Wo);
    }

    // 6) bn3 stats on h2 (bf16)
    bn_stats_kernel<bf16><<<C2, 256, 0, stream>>>(h2, bn3_g, bn3_b, scale3, shift3, C2, SP2, N);

    // 7) conv3: d_out = conv1x1(bn3(h2), w3t)  [N,1024,14,14] fp32
    {
        dim3 grid(1, C3 / 8, N);
        conv1x1_kernel<8, true, bf16, float><<<grid, 256, 0, stream>>>(
            h2, w3t, scale3, shift3, out, C2, C3, Ho, Wo, Ho, Wo, 1);
    }

    // 8) ds conv: sc = conv1x1(x, ds_w RAW, stride2)  [N,1024,14,14] bf16 (aliases h1)
    {
        dim3 grid(1, C3 / 8, N);
        conv1x1_kernel<8, false, float, bf16><<<grid, 256, 0, stream>>>(
            x, ds_w, nullptr, nullptr, sc, C1, C3, H, W, Ho, Wo, 2);
    }

    // 9) ds bn stats on sc (bf16)
    bn_stats_kernel<bf16><<<C3, 256, 0, stream>>>(sc, dbn_g, dbn_b, scaled, shiftd, C3, SP2, N);

    // 10) out += bn(sc)
    {
        size_t total = (size_t)N * C3 * SP2;
        int blocks = (int)((total + 255) / 256);
        bn_add_kernel<<<blocks, 256, 0, stream>>>(sc, scaled, shiftd, out, C3, SP2, total);
    }
}

// Round 4
// 725.740 us; speedup vs baseline: 5.0552x; 5.0552x over previous
//
#include <hip/hip_runtime.h>
#include <hip/hip_bf16.h>
#include <math.h>

#define EPS 1e-5f

typedef __hip_bfloat16 bf16;
typedef short short8 __attribute__((ext_vector_type(8)));
typedef float float4v __attribute__((ext_vector_type(4)));

__device__ __forceinline__ float toF(float v) { return v; }
__device__ __forceinline__ float toF(bf16 v) { return __bfloat162float(v); }
__device__ __forceinline__ void stF(float* p, float v) { *p = v; }
__device__ __forceinline__ void stF(bf16* p, float v) { *p = __float2bfloat16(v); }
__device__ __forceinline__ short f2bs(float v) {
    bf16 b = __float2bfloat16(v);
    return *reinterpret_cast<short*>(&b);
}

// ---------------- block reduction (blockDim.x == 256) ----------------
__device__ __forceinline__ float block_reduce_sum(float v) {
    __shared__ float s[256];
    int t = threadIdx.x;
    s[t] = v;
    __syncthreads();
    #pragma unroll
    for (int st = 128; st > 0; st >>= 1) {
        if (t < st) s[t] += s[t + st];
        __syncthreads();
    }
    float r = s[0];
    __syncthreads();
    return r;
}

// ---------------- ternarize -> bf16 {-1,0,+1} + fp32 alpha ----------------
__global__ void ternarize_kernel(const float* __restrict__ w, short* __restrict__ wt,
                                 float* __restrict__ alpha, int K) {
    int f = blockIdx.x;
    const float* wf = w + (size_t)f * K;
    short* wtf = wt + (size_t)f * K;

    float s = 0.f;
    for (int i = threadIdx.x; i < K; i += blockDim.x) s += fabsf(wf[i]);
    float total = block_reduce_sum(s);
    float delta = 0.7f * total / (float)K;

    float sm = 0.f, cm = 0.f;
    for (int i = threadIdx.x; i < K; i += blockDim.x) {
        float a = fabsf(wf[i]);
        if (a > delta) { sm += a; cm += 1.f; }
    }
    sm = block_reduce_sum(sm);
    cm = block_reduce_sum(cm);
    if (threadIdx.x == 0) alpha[f] = sm / (cm + 1e-8f);

    for (int i = threadIdx.x; i < K; i += blockDim.x) {
        float v = wf[i];
        float a = fabsf(v);
        // bf16 bits: +1 = 0x3F80, -1 = 0xBF80, 0 = 0
        wtf[i] = (a > delta) ? ((v > 0.f) ? (short)0x3F80 : (short)0xBF80) : (short)0;
    }
}

// ---------------- fp32 -> bf16 cast ----------------
__global__ void f2bf_kernel(const float* __restrict__ in, short* __restrict__ out, int n) {
    int i = blockIdx.x * blockDim.x + threadIdx.x;
    if (i < n) out[i] = f2bs(in[i]);
}

// ---------------- BN stats -> per-channel scale/shift ----------------
template <typename T>
__global__ void bn_stats_kernel(const T* __restrict__ src,
                                const float* __restrict__ g, const float* __restrict__ b,
                                float* __restrict__ scale, float* __restrict__ shift,
                                int C, int spatial, int N) {
    int c = blockIdx.x;
    float s = 0.f, s2 = 0.f;
    for (int n = 0; n < N; n++) {
        const T* p = src + ((size_t)n * C + c) * spatial;
        for (int i = threadIdx.x; i < spatial; i += blockDim.x) {
            float v = toF(p[i]);
            s += v;
            s2 += v * v;
        }
    }
    s = block_reduce_sum(s);
    s2 = block_reduce_sum(s2);
    if (threadIdx.x == 0) {
        float cnt = (float)N * (float)spatial;
        float mean = s / cnt;
        float var = fmaxf(s2 / cnt - mean * mean, 0.f);
        float r = rsqrtf(var + EPS);
        float sc = g[c] * r;
        scale[c] = sc;
        shift[c] = b[c] - mean * sc;
    }
}

// ---------------- affine transpose: in[n][C][SPin] -> Bt[(n*SPout+p)][C] bf16 ----------------
// STRIDED: p indexes 14x14 output, input pixel = (2*oh)*Win + 2*ow (Win=28)
template <typename TIn, bool AFFINE, bool STRIDED>
__global__ __launch_bounds__(256) void affine_transpose_kernel(
    const TIn* __restrict__ in, const float* __restrict__ scale,
    const float* __restrict__ shift, short* __restrict__ Bt,
    int C, int SPin, int SPout, int Wout, int Win) {
    __shared__ short tile[64][65];
    int n = blockIdx.z;
    int ci0 = blockIdx.y * 64;
    int p0 = blockIdx.x * 64;
    int tx = threadIdx.x & 63;
    int ty4 = threadIdx.x >> 6;  // 0..3

    int p = p0 + tx;
    int pin = p;
    if (STRIDED) { int oh = p / Wout, ow = p - oh * Wout; pin = oh * 2 * Win + ow * 2; }
    bool pok = p < SPout;
    const TIn* base = in + ((size_t)n * C + ci0) * SPin;
    #pragma unroll
    for (int r = 0; r < 16; r++) {
        int ci = ty4 + r * 4;
        float v = 0.f;
        if (pok) v = toF(base[(size_t)ci * SPin + pin]);
        if (AFFINE) v = v * scale[ci0 + ci] + shift[ci0 + ci];
        tile[tx][ci] = f2bs(v);
    }
    __syncthreads();
    #pragma unroll
    for (int r = 0; r < 16; r++) {
        int pl = ty4 + r * 4;
        int pw = p0 + pl;
        if (pw < SPout)
            Bt[((size_t)n * SPout + pw) * C + ci0 + tx] = tile[pl][tx];
    }
}

// ---------------- im2col + affine for conv2 (3x3 s2 p1) ----------------
// B2t[c][k], c=(n,p14), k=(ci,kh,kw); linear index i = c*2304+k
__global__ void im2col_kernel(const bf16* __restrict__ h1,
                              const float* __restrict__ scale, const float* __restrict__ shift,
                              short* __restrict__ B2t, int total) {
    int i = blockIdx.x * blockDim.x + threadIdx.x;
    if (i >= total) return;
    int k = i % 2304;
    int c = i / 2304;
    int ci = k / 9;
    int rr = k - ci * 9;
    int kh = rr / 3, kw = rr - kh * 3;
    int n = c / 196;
    int pp = c - n * 196;
    int oh = pp / 14, ow = pp - oh * 14;
    int ih = 2 * oh - 1 + kh;
    int iw = 2 * ow - 1 + kw;
    float v = 0.f;
    if ((unsigned)ih < 28u && (unsigned)iw < 28u)
        v = toF(h1[((size_t)n * 256 + ci) * 784 + ih * 28 + iw]) * scale[ci] + shift[ci];
    B2t[i] = f2bs(v);
}

// ---------------- MFMA GEMM: out[n][M][SP] = alpha[m] * (A . Bt^T) ----------------
// A: M x K bf16 row-major; Bt: Ntot x K bf16 row-major (Ntot = 64*SP)
// tile 128(M) x 128(N), BK=32; 4 waves, each 64x64 via 4x4 mfma_f32_16x16x32_bf16
template <int SP, typename TOut, bool HAS_ALPHA>
__global__ __launch_bounds__(256) void gemm_kernel(
    const short* __restrict__ A, const short* __restrict__ Bt,
    const float* __restrict__ alpha, TOut* __restrict__ out,
    int M, int K) {
    __shared__ short As[128 * 32];
    __shared__ short Bs[128 * 32];
    int t = threadIdx.x;
    int c0 = blockIdx.x * 128;
    int m0 = blockIdx.y * 128;
    int w = t >> 6, l = t & 63;
    int wm = (w >> 1) * 64, wn = (w & 1) * 64;

    // staging map: rows r0 and r0+64, k-group kg (8 shorts = 16B)
    int r0 = t >> 2;
    int kg = (t & 3) * 8;

    float4v acc[4][4];
    #pragma unroll
    for (int i = 0; i < 4; i++)
        #pragma unroll
        for (int j = 0; j < 4; j++) acc[i][j] = (float4v)0.f;

    int lm = (l >> 4);       // 0..3 (k-group / row-quad selector)
    int lc = l & 15;

    for (int k0 = 0; k0 < K; k0 += 32) {
        int4 av0 = *(const int4*)(A + (size_t)(m0 + r0) * K + k0 + kg);
        int4 av1 = *(const int4*)(A + (size_t)(m0 + r0 + 64) * K + k0 + kg);
        int4 bv0 = *(const int4*)(Bt + (size_t)(c0 + r0) * K + k0 + kg);
        int4 bv1 = *(const int4*)(Bt + (size_t)(c0 + r0 + 64) * K + k0 + kg);
        __syncthreads();
        *(int4*)&As[r0 * 32 + kg] = av0;
        *(int4*)&As[(r0 + 64) * 32 + kg] = av1;
        *(int4*)&Bs[r0 * 32 + kg] = bv0;
        *(int4*)&Bs[(r0 + 64) * 32 + kg] = bv1;
        __syncthreads();

        short8 af[4], bfr[4];
        #pragma unroll
        for (int i = 0; i < 4; i++)
            af[i] = *(const short8*)&As[(wm + i * 16 + lc) * 32 + lm * 8];
        #pragma unroll
        for (int j = 0; j < 4; j++)
            bfr[j] = *(const short8*)&Bs[(wn + j * 16 + lc) * 32 + lm * 8];
        #pragma unroll
        for (int i = 0; i < 4; i++)
            #pragma unroll
            for (int j = 0; j < 4; j++)
                acc[i][j] = __builtin_amdgcn_mfma_f32_16x16x32_bf16(af[i], bfr[j], acc[i][j], 0, 0, 0);
    }

    // epilogue: D row = 4*(l>>4)+r (M dim), col = l&15 (N dim)  [m89-verified]
    #pragma unroll
    for (int i = 0; i < 4; i++) {
        #pragma unroll
        for (int r = 0; r < 4; r++) {
            int m = m0 + wm + i * 16 + lm * 4 + r;
            float a = HAS_ALPHA ? alpha[m] : 1.f;
            #pragma unroll
            for (int j = 0; j < 4; j++) {
                int c = c0 + wn + j * 16 + lc;
                int n = c / SP;          // SP is a compile-time constant -> magic mul
                int p = c - n * SP;
                stF(&out[((size_t)n * M + m) * SP + p], acc[i][j][r] * a);
            }
        }
    }
}

// ---------------- final: out += sc*scale + shift ----------------
__global__ void bn_add_kernel(const bf16* __restrict__ scv,
                              const float* __restrict__ scale, const float* __restrict__ shift,
                              float* __restrict__ out, int C, int spatial, size_t total) {
    size_t i = (size_t)blockIdx.x * blockDim.x + threadIdx.x;
    if (i >= total) return;
    int c = (int)((i / (size_t)spatial) % (size_t)C);
    out[i] += toF(scv[i]) * scale[c] + shift[c];
}

extern "C" void kernel_launch(void* const* d_in, const int* in_sizes, int n_in,
                              void* d_out, int out_size, void* d_ws, size_t ws_size,
                              hipStream_t stream) {
    const float* x      = (const float*)d_in[0];   // (64,512,28,28)
    const float* bn1_g  = (const float*)d_in[1];
    const float* bn1_b  = (const float*)d_in[2];
    const float* w1     = (const float*)d_in[3];   // (256,512,1,1)
    const float* bn2_g  = (const float*)d_in[4];
    const float* bn2_b  = (const float*)d_in[5];
    const float* w2     = (const float*)d_in[6];   // (256,256,3,3)
    const float* bn3_g  = (const float*)d_in[7];
    const float* bn3_b  = (const float*)d_in[8];
    const float* w3     = (const float*)d_in[9];   // (1024,256,1,1)
    const float* ds_w   = (const float*)d_in[10];  // (1024,512,1,1) NOT ternarized
    const float* dbn_g  = (const float*)d_in[11];
    const float* dbn_b  = (const float*)d_in[12];
    float* out = (float*)d_out;

    const int N = 64, C1 = 512, C2 = 256, C3 = 1024;
    const int SP1 = 784, SP2 = 196;
    const int NT1 = N * SP1;   // 50176
    const int NT2 = N * SP2;   // 12544

    // ---- workspace layout (16B-aligned chunks) ----
    char* wsb = (char*)d_ws;
    size_t off = 0;
    auto alloc = [&](size_t bytes) { char* p = wsb + off; off += (bytes + 255) & ~(size_t)255; return p; };

    // pool: B1t (51.4MB) / B2t (57.8MB) / B3t (6.4MB) / B4t (12.8MB) time-share;
    // sc lives at pool+32MB overlapping only B4t's tail-free region.
    char* pool = alloc((size_t)NT2 * 2304 * 2);          // 57.8 MB
    short* B1t = (short*)pool;                            // [NT1][512]
    short* B2t = (short*)pool;                            // [NT2][2304]
    short* B3t = (short*)pool;                            // [NT2][256]
    short* B4t = (short*)pool;                            // [NT2][512]  (12.8MB)
    bf16*  sc  = (bf16*)(pool + (size_t)32 * 1024 * 1024); // [N][1024][196] 25.7MB

    bf16* h1 = (bf16*)alloc((size_t)N * C2 * SP1 * 2);   // 25.7 MB
    bf16* h2 = (bf16*)alloc((size_t)N * C2 * SP2 * 2);   // 6.4 MB
    short* w1t  = (short*)alloc((size_t)C2 * C1 * 2);
    short* w2t  = (short*)alloc((size_t)C2 * C2 * 9 * 2);
    short* w3t  = (short*)alloc((size_t)C3 * C2 * 2);
    short* dswb = (short*)alloc((size_t)C3 * C1 * 2);
    float* alpha1 = (float*)alloc(C2 * 4);
    float* alpha2 = (float*)alloc(C2 * 4);
    float* alpha3 = (float*)alloc(C3 * 4);
    float* scale1 = (float*)alloc(C1 * 4);
    float* shift1 = (float*)alloc(C1 * 4);
    float* scale2 = (float*)alloc(C2 * 4);
    float* shift2 = (float*)alloc(C2 * 4);
    float* scale3 = (float*)alloc(C2 * 4);
    float* shift3 = (float*)alloc(C2 * 4);
    float* scaled = (float*)alloc(C3 * 4);
    float* shiftd = (float*)alloc(C3 * 4);
    (void)ws_size; (void)in_sizes; (void)n_in; (void)out_size;

    // 1) weights
    ternarize_kernel<<<C2, 256, 0, stream>>>(w1, w1t, alpha1, C1);
    ternarize_kernel<<<C2, 256, 0, stream>>>(w2, w2t, alpha2, C2 * 9);
    ternarize_kernel<<<C3, 256, 0, stream>>>(w3, w3t, alpha3, C2);
    f2bf_kernel<<<(C3 * C1 + 255) / 256, 256, 0, stream>>>(ds_w, dswb, C3 * C1);

    // 2) bn1 stats + B1t = bn1(x)^T bf16
    bn_stats_kernel<float><<<C1, 256, 0, stream>>>(x, bn1_g, bn1_b, scale1, shift1, C1, SP1, N);
    {
        dim3 grid((SP1 + 63) / 64, C1 / 64, N);  // (13, 8, 64)
        affine_transpose_kernel<float, true, false><<<grid, 256, 0, stream>>>(
            x, scale1, shift1, B1t, C1, SP1, SP1, 0, 0);
    }

    // 3) GEMM1: h1 = alpha1 * (w1t . B1t^T)   M=256 K=512 SP=784
    gemm_kernel<784, bf16, true><<<dim3(NT1 / 128, C2 / 128), 256, 0, stream>>>(
        w1t, B1t, alpha1, h1, C2, C1);

    // 4) bn2 stats + im2col(B2t)
    bn_stats_kernel<bf16><<<C2, 256, 0, stream>>>(h1, bn2_g, bn2_b, scale2, shift2, C2, SP1, N);
    {
        int total = NT2 * 2304;
        im2col_kernel<<<(total + 255) / 256, 256, 0, stream>>>(h1, scale2, shift2, B2t, total);
    }

    // 5) GEMM2: h2 = alpha2 * (w2t . B2t^T)   M=256 K=2304 SP=196
    gemm_kernel<196, bf16, true><<<dim3(NT2 / 128, C2 / 128), 256, 0, stream>>>(
        w2t, B2t, alpha2, h2, C2, C2 * 9);

    // 6) bn3 stats + B3t = bn3(h2)^T
    bn_stats_kernel<bf16><<<C2, 256, 0, stream>>>(h2, bn3_g, bn3_b, scale3, shift3, C2, SP2, N);
    {
        dim3 grid((SP2 + 63) / 64, C2 / 64, N);  // (4, 4, 64)
        affine_transpose_kernel<bf16, true, false><<<grid, 256, 0, stream>>>(
            h2, scale3, shift3, B3t, C2, SP2, SP2, 0, 0);
    }

    // 7) GEMM3: d_out = alpha3 * (w3t . B3t^T)  M=1024 K=256 SP=196, fp32 out
    gemm_kernel<196, float, true><<<dim3(NT2 / 128, C3 / 128), 256, 0, stream>>>(
        w3t, B3t, alpha3, out, C3, C2);

    // 8) B4t = x strided s2 (no affine), then GEMM4: sc = dswb . B4t^T
    {
        dim3 grid((SP2 + 63) / 64, C1 / 64, N);  // (4, 8, 64)
        affine_transpose_kernel<float, false, true><<<grid, 256, 0, stream>>>(
            x, nullptr, nullptr, B4t, C1, SP1, SP2, 14, 28);
    }
    gemm_kernel<196, bf16, false><<<dim3(NT2 / 128, C3 / 128), 256, 0, stream>>>(
        dswb, B4t, nullptr, sc, C3, C1);

    // 9) ds bn stats + residual add
    bn_stats_kernel<bf16><<<C3, 256, 0, stream>>>(sc, dbn_g, dbn_b, scaled, shiftd, C3, SP2, N);
    {
        size_t total = (size_t)N * C3 * SP2;
        bn_add_kernel<<<(int)((total + 255) / 256), 256, 0, stream>>>(
            sc, scaled, shiftd, out, C3, SP2, total);
    }
}

// Round 5
// 542.866 us; speedup vs baseline: 6.7582x; 1.3369x over previous
//
#include <hip/hip_runtime.h>
#include <hip/hip_bf16.h>
#include <math.h>

#define EPS 1e-5f

typedef __hip_bfloat16 bf16;
typedef short short8 __attribute__((ext_vector_type(8)));
typedef float float4v __attribute__((ext_vector_type(4)));

__device__ __forceinline__ float toF(float v) { return v; }
__device__ __forceinline__ float toF(bf16 v) { return __bfloat162float(v); }
__device__ __forceinline__ void stF(float* p, float v) { *p = v; }
__device__ __forceinline__ void stF(bf16* p, float v) { *p = __float2bfloat16(v); }
__device__ __forceinline__ short f2bs(float v) {
    bf16 b = __float2bfloat16(v);
    return *reinterpret_cast<short*>(&b);
}
__device__ __forceinline__ float bs2f(short s) {
    unsigned u = ((unsigned)(unsigned short)s) << 16;
    return __uint_as_float(u);
}

// ---------------- block reduction (blockDim.x == 256) ----------------
__device__ __forceinline__ float block_reduce_sum(float v) {
    __shared__ float s[256];
    int t = threadIdx.x;
    s[t] = v;
    __syncthreads();
    #pragma unroll
    for (int st = 128; st > 0; st >>= 1) {
        if (t < st) s[t] += s[t + st];
        __syncthreads();
    }
    float r = s[0];
    __syncthreads();
    return r;
}

// ---------------- ternarize -> bf16 {-1,0,+1} + fp32 alpha ----------------
__global__ void ternarize_kernel(const float* __restrict__ w, short* __restrict__ wt,
                                 float* __restrict__ alpha, int K) {
    int f = blockIdx.x;
    const float* wf = w + (size_t)f * K;
    short* wtf = wt + (size_t)f * K;

    float s = 0.f;
    for (int i = threadIdx.x; i < K; i += blockDim.x) s += fabsf(wf[i]);
    float total = block_reduce_sum(s);
    float delta = 0.7f * total / (float)K;

    float sm = 0.f, cm = 0.f;
    for (int i = threadIdx.x; i < K; i += blockDim.x) {
        float a = fabsf(wf[i]);
        if (a > delta) { sm += a; cm += 1.f; }
    }
    sm = block_reduce_sum(sm);
    cm = block_reduce_sum(cm);
    if (threadIdx.x == 0) alpha[f] = sm / (cm + 1e-8f);

    for (int i = threadIdx.x; i < K; i += blockDim.x) {
        float v = wf[i];
        float a = fabsf(v);
        wtf[i] = (a > delta) ? ((v > 0.f) ? (short)0x3F80 : (short)0xBF80) : (short)0;
    }
}

// ---------------- fp32 -> bf16 cast ----------------
__global__ void f2bf_kernel(const float* __restrict__ in, short* __restrict__ out, int n) {
    int i = blockIdx.x * blockDim.x + threadIdx.x;
    if (i < n) out[i] = f2bs(in[i]);
}

// ---------------- BN stats phase A: vectorized partial sums + atomics ----------------
// grid (C, splits), block 256. Accumulators must be pre-zeroed.
template <typename T, int VEC>
__global__ __launch_bounds__(256) void bn_sum_kernel(
    const T* __restrict__ src, float* __restrict__ sum, float* __restrict__ sq,
    int C, int spatial, int N, int splits) {
    int c = blockIdx.x;
    int vpc = spatial / VEC;          // vectors per (n,c) chunk
    int total = N * vpc;
    float s = 0.f, s2 = 0.f;
    for (int v = blockIdx.y * 256 + threadIdx.x; v < total; v += splits * 256) {
        int n = v / vpc;
        int i = v - n * vpc;
        const T* p = src + ((size_t)n * C + c) * spatial + i * VEC;
        float vals[VEC];
        if (sizeof(T) == 4) {
            // fp32: VEC==4, one float4
            float4 q = *(const float4*)p;
            vals[0] = q.x; vals[1] = q.y; vals[2] = q.z; vals[3] = q.w;
        } else {
            // bf16: VEC==8 (int4) or VEC==4 (int2)
            short tmp[VEC];
            if (VEC == 8) *(int4*)tmp = *(const int4*)p;
            else          *(int2*)tmp = *(const int2*)p;
            #pragma unroll
            for (int k = 0; k < VEC; k++) vals[k] = bs2f(tmp[k]);
        }
        #pragma unroll
        for (int k = 0; k < VEC; k++) { s += vals[k]; s2 += vals[k] * vals[k]; }
    }
    s = block_reduce_sum(s);
    s2 = block_reduce_sum(s2);
    if (threadIdx.x == 0) {
        atomicAdd(&sum[c], s);
        atomicAdd(&sq[c], s2);
    }
}

// ---------------- BN stats phase B: finalize scale/shift ----------------
__global__ void bn_finalize_kernel(const float* __restrict__ sum, const float* __restrict__ sq,
                                   const float* __restrict__ g, const float* __restrict__ b,
                                   float* __restrict__ scale, float* __restrict__ shift,
                                   int C, float cnt) {
    int c = blockIdx.x * blockDim.x + threadIdx.x;
    if (c >= C) return;
    float mean = sum[c] / cnt;
    float var = fmaxf(sq[c] / cnt - mean * mean, 0.f);
    float r = rsqrtf(var + EPS);
    float sc = g[c] * r;
    scale[c] = sc;
    shift[c] = b[c] - mean * sc;
}

// ---------------- affine transpose: in[n][C][SPin] -> Bt[(n*SPout+p)][C] bf16 ----------------
template <typename TIn, bool AFFINE, bool STRIDED>
__global__ __launch_bounds__(256) void affine_transpose_kernel(
    const TIn* __restrict__ in, const float* __restrict__ scale,
    const float* __restrict__ shift, short* __restrict__ Bt,
    int C, int SPin, int SPout, int Wout, int Win) {
    __shared__ short tile[64][65];
    int n = blockIdx.z;
    int ci0 = blockIdx.y * 64;
    int p0 = blockIdx.x * 64;
    int tx = threadIdx.x & 63;
    int ty4 = threadIdx.x >> 6;  // 0..3

    int p = p0 + tx;
    int pin = p;
    if (STRIDED) { int oh = p / Wout, ow = p - oh * Wout; pin = oh * 2 * Win + ow * 2; }
    bool pok = p < SPout;
    const TIn* base = in + ((size_t)n * C + ci0) * SPin;
    #pragma unroll
    for (int r = 0; r < 16; r++) {
        int ci = ty4 + r * 4;
        float v = 0.f;
        if (pok) v = toF(base[(size_t)ci * SPin + pin]);
        if (AFFINE) v = v * scale[ci0 + ci] + shift[ci0 + ci];
        tile[tx][ci] = f2bs(v);
    }
    __syncthreads();
    #pragma unroll
    for (int r = 0; r < 16; r++) {
        int pl = ty4 + r * 4;
        int pw = p0 + pl;
        if (pw < SPout)
            Bt[((size_t)n * SPout + pw) * C + ci0 + tx] = tile[pl][tx];
    }
}

// ---------------- im2col + affine for conv2 (3x3 s2 p1) ----------------
__global__ void im2col_kernel(const bf16* __restrict__ h1,
                              const float* __restrict__ scale, const float* __restrict__ shift,
                              short* __restrict__ B2t, int total) {
    int i = blockIdx.x * blockDim.x + threadIdx.x;
    if (i >= total) return;
    int k = i % 2304;
    int c = i / 2304;
    int ci = k / 9;
    int rr = k - ci * 9;
    int kh = rr / 3, kw = rr - kh * 3;
    int n = c / 196;
    int pp = c - n * 196;
    int oh = pp / 14, ow = pp - oh * 14;
    int ih = 2 * oh - 1 + kh;
    int iw = 2 * ow - 1 + kw;
    float v = 0.f;
    if ((unsigned)ih < 28u && (unsigned)iw < 28u)
        v = toF(h1[((size_t)n * 256 + ci) * 784 + ih * 28 + iw]) * scale[ci] + shift[ci];
    B2t[i] = f2bs(v);
}

// ---------------- MFMA GEMM (128x128 tile, BK=32, 4 waves, 4x4 16x16x32) ----------------
template <int SP, typename TOut, bool HAS_ALPHA>
__global__ __launch_bounds__(256) void gemm_kernel(
    const short* __restrict__ A, const short* __restrict__ Bt,
    const float* __restrict__ alpha, TOut* __restrict__ out,
    int M, int K) {
    __shared__ short As[128 * 32];
    __shared__ short Bs[128 * 32];
    int t = threadIdx.x;
    int c0 = blockIdx.x * 128;
    int m0 = blockIdx.y * 128;
    int w = t >> 6, l = t & 63;
    int wm = (w >> 1) * 64, wn = (w & 1) * 64;

    int r0 = t >> 2;
    int kg = (t & 3) * 8;

    float4v acc[4][4];
    #pragma unroll
    for (int i = 0; i < 4; i++)
        #pragma unroll
        for (int j = 0; j < 4; j++) acc[i][j] = (float4v)0.f;

    int lm = (l >> 4);
    int lc = l & 15;

    for (int k0 = 0; k0 < K; k0 += 32) {
        int4 av0 = *(const int4*)(A + (size_t)(m0 + r0) * K + k0 + kg);
        int4 av1 = *(const int4*)(A + (size_t)(m0 + r0 + 64) * K + k0 + kg);
        int4 bv0 = *(const int4*)(Bt + (size_t)(c0 + r0) * K + k0 + kg);
        int4 bv1 = *(const int4*)(Bt + (size_t)(c0 + r0 + 64) * K + k0 + kg);
        __syncthreads();
        *(int4*)&As[r0 * 32 + kg] = av0;
        *(int4*)&As[(r0 + 64) * 32 + kg] = av1;
        *(int4*)&Bs[r0 * 32 + kg] = bv0;
        *(int4*)&Bs[(r0 + 64) * 32 + kg] = bv1;
        __syncthreads();

        short8 af[4], bfr[4];
        #pragma unroll
        for (int i = 0; i < 4; i++)
            af[i] = *(const short8*)&As[(wm + i * 16 + lc) * 32 + lm * 8];
        #pragma unroll
        for (int j = 0; j < 4; j++)
            bfr[j] = *(const short8*)&Bs[(wn + j * 16 + lc) * 32 + lm * 8];
        #pragma unroll
        for (int i = 0; i < 4; i++)
            #pragma unroll
            for (int j = 0; j < 4; j++)
                acc[i][j] = __builtin_amdgcn_mfma_f32_16x16x32_bf16(af[i], bfr[j], acc[i][j], 0, 0, 0);
    }

    #pragma unroll
    for (int i = 0; i < 4; i++) {
        #pragma unroll
        for (int r = 0; r < 4; r++) {
            int m = m0 + wm + i * 16 + lm * 4 + r;
            float a = HAS_ALPHA ? alpha[m] : 1.f;
            #pragma unroll
            for (int j = 0; j < 4; j++) {
                int c = c0 + wn + j * 16 + lc;
                int n = c / SP;
                int p = c - n * SP;
                stF(&out[((size_t)n * M + m) * SP + p], acc[i][j][r] * a);
            }
        }
    }
}

// ---------------- final: out += sc*scale + shift ----------------
__global__ void bn_add_kernel(const bf16* __restrict__ scv,
                              const float* __restrict__ scale, const float* __restrict__ shift,
                              float* __restrict__ out, int C, int spatial, size_t total) {
    size_t i = (size_t)blockIdx.x * blockDim.x + threadIdx.x;
    if (i >= total) return;
    int c = (int)((i / (size_t)spatial) % (size_t)C);
    out[i] += toF(scv[i]) * scale[c] + shift[c];
}

extern "C" void kernel_launch(void* const* d_in, const int* in_sizes, int n_in,
                              void* d_out, int out_size, void* d_ws, size_t ws_size,
                              hipStream_t stream) {
    const float* x      = (const float*)d_in[0];   // (64,512,28,28)
    const float* bn1_g  = (const float*)d_in[1];
    const float* bn1_b  = (const float*)d_in[2];
    const float* w1     = (const float*)d_in[3];   // (256,512,1,1)
    const float* bn2_g  = (const float*)d_in[4];
    const float* bn2_b  = (const float*)d_in[5];
    const float* w2     = (const float*)d_in[6];   // (256,256,3,3)
    const float* bn3_g  = (const float*)d_in[7];
    const float* bn3_b  = (const float*)d_in[8];
    const float* w3     = (const float*)d_in[9];   // (1024,256,1,1)
    const float* ds_w   = (const float*)d_in[10];  // (1024,512,1,1) NOT ternarized
    const float* dbn_g  = (const float*)d_in[11];
    const float* dbn_b  = (const float*)d_in[12];
    float* out = (float*)d_out;

    const int N = 64, C1 = 512, C2 = 256, C3 = 1024;
    const int SP1 = 784, SP2 = 196;
    const int NT1 = N * SP1;   // 50176
    const int NT2 = N * SP2;   // 12544

    // ---- workspace layout ----
    char* wsb = (char*)d_ws;
    size_t off = 0;
    auto alloc = [&](size_t bytes) { char* p = wsb + off; off += (bytes + 255) & ~(size_t)255; return p; };

    char* pool = alloc((size_t)NT2 * 2304 * 2);          // 57.8 MB (B1t/B2t/B3t/B4t time-share)
    short* B1t = (short*)pool;
    short* B2t = (short*)pool;
    short* B3t = (short*)pool;
    short* B4t = (short*)pool;
    bf16*  sc  = (bf16*)(pool + (size_t)32 * 1024 * 1024); // 25.7MB, after B4t's 12.8MB

    bf16* h1 = (bf16*)alloc((size_t)N * C2 * SP1 * 2);
    bf16* h2 = (bf16*)alloc((size_t)N * C2 * SP2 * 2);
    short* w1t  = (short*)alloc((size_t)C2 * C1 * 2);
    short* w2t  = (short*)alloc((size_t)C2 * C2 * 9 * 2);
    short* w3t  = (short*)alloc((size_t)C3 * C2 * 2);
    short* dswb = (short*)alloc((size_t)C3 * C1 * 2);
    float* alpha1 = (float*)alloc(C2 * 4);
    float* alpha2 = (float*)alloc(C2 * 4);
    float* alpha3 = (float*)alloc(C3 * 4);
    float* scale1 = (float*)alloc(C1 * 4);
    float* shift1 = (float*)alloc(C1 * 4);
    float* scale2 = (float*)alloc(C2 * 4);
    float* shift2 = (float*)alloc(C2 * 4);
    float* scale3 = (float*)alloc(C2 * 4);
    float* shift3 = (float*)alloc(C2 * 4);
    float* scaled = (float*)alloc(C3 * 4);
    float* shiftd = (float*)alloc(C3 * 4);
    // BN accumulators (contiguous so one memset clears all): 512+256+256+1024 channels x2
    float* acc_base = (float*)alloc((size_t)(C1 + C2 + C2 + C3) * 2 * 4);
    float* sum1 = acc_base;            float* sq1 = sum1 + C1;
    float* sum2 = sq1 + C1;            float* sq2 = sum2 + C2;
    float* sum3 = sq2 + C2;            float* sq3 = sum3 + C2;
    float* sumd = sq3 + C2;            float* sqd = sumd + C3;
    (void)ws_size; (void)in_sizes; (void)n_in; (void)out_size;

    // 0) zero BN accumulators (capture-safe async memset)
    hipMemsetAsync(acc_base, 0, (size_t)(C1 + C2 + C2 + C3) * 2 * 4, stream);

    // 1) weights
    ternarize_kernel<<<C2, 256, 0, stream>>>(w1, w1t, alpha1, C1);
    ternarize_kernel<<<C2, 256, 0, stream>>>(w2, w2t, alpha2, C2 * 9);
    ternarize_kernel<<<C3, 256, 0, stream>>>(w3, w3t, alpha3, C2);
    f2bf_kernel<<<(C3 * C1 + 255) / 256, 256, 0, stream>>>(ds_w, dswb, C3 * C1);

    // 2) bn1 stats (fast) + B1t = bn1(x)^T bf16
    bn_sum_kernel<float, 4><<<dim3(C1, 8), 256, 0, stream>>>(x, sum1, sq1, C1, SP1, N, 8);
    bn_finalize_kernel<<<(C1 + 255) / 256, 256, 0, stream>>>(sum1, sq1, bn1_g, bn1_b,
                                                             scale1, shift1, C1, (float)(N * SP1));
    {
        dim3 grid((SP1 + 63) / 64, C1 / 64, N);
        affine_transpose_kernel<float, true, false><<<grid, 256, 0, stream>>>(
            x, scale1, shift1, B1t, C1, SP1, SP1, 0, 0);
    }

    // 3) GEMM1: h1 = alpha1 * (w1t . B1t^T)   M=256 K=512 SP=784
    gemm_kernel<784, bf16, true><<<dim3(NT1 / 128, C2 / 128), 256, 0, stream>>>(
        w1t, B1t, alpha1, h1, C2, C1);

    // 4) bn2 stats (fast) + im2col(B2t)
    bn_sum_kernel<bf16, 8><<<dim3(C2, 8), 256, 0, stream>>>(h1, sum2, sq2, C2, SP1, N, 8);
    bn_finalize_kernel<<<(C2 + 255) / 256, 256, 0, stream>>>(sum2, sq2, bn2_g, bn2_b,
                                                             scale2, shift2, C2, (float)(N * SP1));
    {
        int total = NT2 * 2304;
        im2col_kernel<<<(total + 255) / 256, 256, 0, stream>>>(h1, scale2, shift2, B2t, total);
    }

    // 5) GEMM2: h2 = alpha2 * (w2t . B2t^T)   M=256 K=2304 SP=196
    gemm_kernel<196, bf16, true><<<dim3(NT2 / 128, C2 / 128), 256, 0, stream>>>(
        w2t, B2t, alpha2, h2, C2, C2 * 9);

    // 6) bn3 stats (fast) + B3t = bn3(h2)^T
    bn_sum_kernel<bf16, 4><<<dim3(C2, 4), 256, 0, stream>>>(h2, sum3, sq3, C2, SP2, N, 4);
    bn_finalize_kernel<<<(C2 + 255) / 256, 256, 0, stream>>>(sum3, sq3, bn3_g, bn3_b,
                                                             scale3, shift3, C2, (float)(N * SP2));
    {
        dim3 grid((SP2 + 63) / 64, C2 / 64, N);
        affine_transpose_kernel<bf16, true, false><<<grid, 256, 0, stream>>>(
            h2, scale3, shift3, B3t, C2, SP2, SP2, 0, 0);
    }

    // 7) GEMM3: d_out = alpha3 * (w3t . B3t^T)  M=1024 K=256 SP=196, fp32 out
    gemm_kernel<196, float, true><<<dim3(NT2 / 128, C3 / 128), 256, 0, stream>>>(
        w3t, B3t, alpha3, out, C3, C2);

    // 8) B4t = x strided s2 (no affine), then GEMM4: sc = dswb . B4t^T
    {
        dim3 grid((SP2 + 63) / 64, C1 / 64, N);
        affine_transpose_kernel<float, false, true><<<grid, 256, 0, stream>>>(
            x, nullptr, nullptr, B4t, C1, SP1, SP2, 14, 28);
    }
    gemm_kernel<196, bf16, false><<<dim3(NT2 / 128, C3 / 128), 256, 0, stream>>>(
        dswb, B4t, nullptr, sc, C3, C1);

    // 9) ds bn stats (fast) + residual add
    bn_sum_kernel<bf16, 4><<<dim3(C3, 4), 256, 0, stream>>>(sc, sumd, sqd, C3, SP2, N, 4);
    bn_finalize_kernel<<<(C3 + 255) / 256, 256, 0, stream>>>(sumd, sqd, dbn_g, dbn_b,
                                                             scaled, shiftd, C3, (float)(N * SP2));
    {
        size_t total = (size_t)N * C3 * SP2;
        bn_add_kernel<<<(int)((total + 255) / 256), 256, 0, stream>>>(
            sc, scaled, shiftd, out, C3, SP2, total);
    }
}